// Round 11
// baseline (3086.653 us; speedup 1.0000x reference)
//
#include <hip/hip_runtime.h>
#include <stdint.h>

#define B 8
#define N 8192
#define NG 512
#define GS 32

typedef unsigned long long ull;
typedef float v2f __attribute__((ext_vector_type(2)));
typedef float v4f __attribute__((ext_vector_type(4)));

// Exact (no-FMA, left-to-right) squared distance: ((dx*dx + dy*dy) + dz*dz)
__device__ __forceinline__ float sq3(float dx, float dy, float dz) {
#pragma clang fp contract(off)
  return dx * dx + dy * dy + dz * dz;
}

// 64-bit max/min via DPP move (pure VALU, no LDS pipe). Invalid lanes keep old.
// Full-wave chain 0x111,0x112,0x114,0x118,0x142,0x143 -> result in lane 63
// (validated R2-R9, absmax stayed 0.0).
template <int CTRL>
__device__ __forceinline__ ull dpp_max64(ull key) {
  unsigned lo = (unsigned)key, hi = (unsigned)(key >> 32);
  unsigned olo = (unsigned)__builtin_amdgcn_update_dpp((int)lo, (int)lo, CTRL, 0xf, 0xf, false);
  unsigned ohi = (unsigned)__builtin_amdgcn_update_dpp((int)hi, (int)hi, CTRL, 0xf, 0xf, false);
  ull o = ((ull)ohi << 32) | olo;
  return (o > key) ? o : key;
}
template <int CTRL>
__device__ __forceinline__ ull dpp_min64(ull key) {
  unsigned lo = (unsigned)key, hi = (unsigned)(key >> 32);
  unsigned olo = (unsigned)__builtin_amdgcn_update_dpp((int)lo, (int)lo, CTRL, 0xf, 0xf, false);
  unsigned ohi = (unsigned)__builtin_amdgcn_update_dpp((int)hi, (int)hi, CTRL, 0xf, 0xf, false);
  ull o = ((ull)ohi << 32) | olo;
  return (o < key) ? o : key;
}

// ---------------- Kernel 1: SE(3) transform, AoS xyz -> SoA xs/ys/zs ------
__global__ void transform_k(const float* __restrict__ xyz,
                            const float* __restrict__ pose,
                            float* __restrict__ xs, float* __restrict__ ys,
                            float* __restrict__ zs) {
#pragma clang fp contract(off)
  int i = blockIdx.x * blockDim.x + threadIdx.x;
  if (i >= B * N) return;
  int b = i / N;
  const float* P = pose + b * 12;  // (3,4) row-major: R|t
  float p0 = xyz[i * 3 + 0], p1 = xyz[i * 3 + 1], p2 = xyz[i * 3 + 2];
  // exact order: ((r0*p0 + r1*p1) + r2*p2) + t
  float ox = ((P[0] * p0 + P[1] * p1) + P[2] * p2) + P[3];
  float oy = ((P[4] * p0 + P[5] * p1) + P[6] * p2) + P[7];
  float oz = ((P[8] * p0 + P[9] * p1) + P[10] * p2) + P[11];
  xs[i] = ox;
  ys[i] = oy;
  zs[i] = oz;
}

// ---------------- Kernel 2: farthest point sampling, 1 block per batch ----
// R10 (resubmitted after infra failure): LDS-home scan tuned from R8/R9:
//  - 512 thr (8 waves, 2/SIMD): covers ds_read latency (R8's 1-wave/SIMD
//    failure) without R9's 4x reduce-issue overhead (16 waves all running
//    the DPP chain).
//  - b128 layout: thread t, iter j owns points (j*512+t)*4+e, e=0..3 ->
//    12 ds_read_b128/thread/step, lane stride 16B = conflict-free, max
//    LDS efficiency (85 B/cyc, m134). LDS pipe ~= 96 b128 * 12cyc = 1150
//    cyc/CU/step, latency hidden by 2 waves/SIMD.
//  - R2's short tail: lane0/wave publishes (key,x,y,z) with coords read
//    from LDS PRE-barrier (overlapped across 8 waves); post-barrier a
//    3-level uniform select tree. No dependent broadcast read (R9's +110).
#define FPS_T 512
#define FPS_W (FPS_T / 64)       // 8 waves
#define FPS_G 4                  // points per b128 group
#define FPS_J (N / FPS_T / FPS_G)  // 4 groups per thread

__global__ __launch_bounds__(FPS_T) void fps_k(const float* __restrict__ xs,
                                               const float* __restrict__ ys,
                                               const float* __restrict__ zs,
                                               float* __restrict__ centers) {
#pragma clang fp contract(off)
  int b = blockIdx.x;
  int t = threadIdx.x;

  __shared__ float plx[N];         // LDS home of this batch's points (SoA)
  __shared__ float ply[N];
  __shared__ float plz[N];
  __shared__ float cbuf[NG * 3];   // buffered centers (flush at end)
  __shared__ ull wkey[2][FPS_W];   // parity-double-buffered per-wave keys
  __shared__ float4 wxyz[2][FPS_W];  // ... and winner coords

  const float* __restrict__ bx = xs + b * N;
  const float* __restrict__ by = ys + b * N;
  const float* __restrict__ bz = zs + b * N;
  const v4f* __restrict__ bx4 = (const v4f*)bx;
  const v4f* __restrict__ by4 = (const v4f*)by;
  const v4f* __restrict__ bz4 = (const v4f*)bz;
  const v4f* plx4 = (const v4f*)plx;
  const v4f* ply4 = (const v4f*)ply;
  const v4f* plz4 = (const v4f*)plz;

  // point (j, t, e) has global index p = (j*FPS_T + t)*4 + e
  v4f dist[FPS_J];
#pragma unroll
  for (int j = 0; j < FPS_J; ++j) {
    int q = j * FPS_T + t;
    ((v4f*)plx)[q] = bx4[q];  // 16B coalesced global load -> LDS
    ((v4f*)ply)[q] = by4[q];
    ((v4f*)plz)[q] = bz4[q];
    dist[j].x = 1e10f;  // matches jnp.full(..., 1e10, f32)
    dist[j].y = 1e10f;
    dist[j].z = 1e10f;
    dist[j].w = 1e10f;
  }

  // initial "last" point is index 0 (broadcast global load, off critical path)
  float lx = bx[0], ly = by[0], lz = bz[0];
  __syncthreads();  // LDS point home ready

  for (int k = 0; k < NG; ++k) {
    if (t == 0) {  // emit 'last' BEFORE update; LDS store (no vmcnt at barrier)
      cbuf[k * 3 + 0] = lx;
      cbuf[k * 3 + 1] = ly;
      cbuf[k * 3 + 2] = lz;
    }

    // Fused exact min-update + first-occurrence argmax, streaming points
    // from LDS via ds_read_b128. 4 accumulators, one per lane-of-4 (e);
    // within acc e, codes j ascend in processing order AND in global idx
    // (idx = (j*T+t)*4+e) => strict '>' keeps first occurrence. Cross-acc
    // merge is tie-aware on full code (j<<2)|e which orders by global idx.
    float bd0 = -1.0f, bd1 = -1.0f, bd2 = -1.0f, bd3 = -1.0f;
    int bj0 = 0, bj1 = 0, bj2 = 0, bj3 = 0;
#pragma unroll
    for (int j = 0; j < FPS_J; ++j) {
      int q = j * FPS_T + t;
      v4f x = plx4[q], y = ply4[q], z = plz4[q];
      v4f dx = x - lx, dy = y - ly, dz = z - lz;
      v4f d = (dx * dx + dy * dy) + dz * dz;
      v4f dc = dist[j];
      v4f dm;
      dm.x = fminf(dc.x, d.x);
      dm.y = fminf(dc.y, d.y);
      dm.z = fminf(dc.z, d.z);
      dm.w = fminf(dc.w, d.w);
      dist[j] = dm;
      bool g0 = dm.x > bd0; bd0 = g0 ? dm.x : bd0; bj0 = g0 ? j : bj0;
      bool g1 = dm.y > bd1; bd1 = g1 ? dm.y : bd1; bj1 = g1 ? j : bj1;
      bool g2 = dm.z > bd2; bd2 = g2 ? dm.z : bd2; bj2 = g2 ? j : bj2;
      bool g3 = dm.w > bd3; bd3 = g3 ? dm.w : bd3; bj3 = g3 ? j : bj3;
    }
    // tie-aware merge on (dist, code) with code = (j<<2)|e (global-idx order)
    int c0 = (bj0 << 2) | 0, c1 = (bj1 << 2) | 1;
    int c2 = (bj2 << 2) | 2, c3 = (bj3 << 2) | 3;
    {
      bool s1 = (bd1 > bd0) || ((bd1 == bd0) && (c1 < c0));
      bd0 = s1 ? bd1 : bd0; c0 = s1 ? c1 : c0;
      bool s2 = (bd3 > bd2) || ((bd3 == bd2) && (c3 < c2));
      bd2 = s2 ? bd3 : bd2; c2 = s2 ? c3 : c2;
      bool s3 = (bd2 > bd0) || ((bd2 == bd0) && (c2 < c0));
      bd0 = s3 ? bd2 : bd0; c0 = s3 ? c2 : c0;
    }
    // reconstruct global point index: idx = ((j*FPS_T + t) << 2) | e
    int cand = (((c0 >> 2) * FPS_T + t) << 2) | (c0 & 3);
    // pack: max over key == max dist, tie -> min index
    ull key = ((ull)__float_as_uint(bd0) << 32) | (ull)(unsigned)(N - 1 - cand);

    // wave-level max via DPP (VALU only), result in lane 63
    key = dpp_max64<0x111>(key);
    key = dpp_max64<0x112>(key);
    key = dpp_max64<0x114>(key);
    key = dpp_max64<0x118>(key);
    key = dpp_max64<0x142>(key);
    key = dpp_max64<0x143>(key);
    unsigned klo = (unsigned)__builtin_amdgcn_readlane((int)(unsigned)key, 63);
    unsigned khi = (unsigned)__builtin_amdgcn_readlane((int)(unsigned)(key >> 32), 63);
    ull wk = ((ull)khi << 32) | klo;

    int kb = k & 1;
    if ((t & 63) == 0) {
      // publish wave winner key + coords (coords via LDS, pre-barrier overlap)
      int wc = (N - 1) - (int)(unsigned)(wk & 0xffffffffu);
      wkey[kb][t >> 6] = wk;
      wxyz[kb][t >> 6] = make_float4(plx[wc], ply[wc], plz[wc], 0.0f);
    }
    __syncthreads();

    // cross-wave merge over 8 partials (uniform reads, 3-level select tree)
    ull k0 = wkey[kb][0], k1 = wkey[kb][1], k2 = wkey[kb][2], k3 = wkey[kb][3];
    ull k4 = wkey[kb][4], k5 = wkey[kb][5], k6 = wkey[kb][6], k7 = wkey[kb][7];
    float4 c0f = wxyz[kb][0], c1f = wxyz[kb][1], c2f = wxyz[kb][2], c3f = wxyz[kb][3];
    float4 c4f = wxyz[kb][4], c5f = wxyz[kb][5], c6f = wxyz[kb][6], c7f = wxyz[kb][7];
    bool s;
    s = k1 > k0; k0 = s ? k1 : k0; c0f = s ? c1f : c0f;
    s = k3 > k2; k2 = s ? k3 : k2; c2f = s ? c3f : c2f;
    s = k5 > k4; k4 = s ? k5 : k4; c4f = s ? c5f : c4f;
    s = k7 > k6; k6 = s ? k7 : k6; c6f = s ? c7f : c6f;
    s = k2 > k0; k0 = s ? k2 : k0; c0f = s ? c2f : c0f;
    s = k6 > k4; k4 = s ? k6 : k4; c4f = s ? c6f : c4f;
    s = k4 > k0; k0 = s ? k4 : k0; c0f = s ? c4f : c0f;
    lx = c0f.x;
    ly = c0f.y;
    lz = c0f.z;
    // no second barrier: next iter writes wkey/wxyz[(k+1)&1] (other buffer)
  }

  // flush centers (B, NG, 3)
  __syncthreads();
  for (int i = t; i < NG * 3; i += FPS_T) centers[b * NG * 3 + i] = cbuf[i];
}

// ---------------- Kernel 3: exact 32-NN per center, 1 block per center ----
// DPP (VALU) u64-min wave reduction + parity-double-buffered partials:
// ONE barrier per extraction round (plus one final before the gather).
#define KNN_T 256
#define KNN_W (KNN_T / 64)
#define KNN_P (N / KNN_T)  // 32 points per thread

__global__ __launch_bounds__(KNN_T, 2) void knn_k(const float* __restrict__ xs,
                                                  const float* __restrict__ ys,
                                                  const float* __restrict__ zs,
                                                  const float* __restrict__ centers,
                                                  float* __restrict__ out) {
#pragma clang fp contract(off)
  int b = blockIdx.y, g = blockIdx.x, t = threadIdx.x;
  const float* bx = xs + b * N;
  const float* by = ys + b * N;
  const float* bz = zs + b * N;
  int ci = (b * NG + g) * 3;
  float cx = centers[ci], cy = centers[ci + 1], cz = centers[ci + 2];

  // packed keys: (distBits<<32)|idx ; min over key == min dist, tie -> min idx
  ull key[KNN_P];
  ull lmin = ~0ull;
#pragma unroll
  for (int j = 0; j < KNN_P; ++j) {
    int p = j * KNN_T + t;
    float dx = bx[p] - cx, dy = by[p] - cy, dz = bz[p] - cz;
    float d = sq3(dx, dy, dz);
    key[j] = ((ull)__float_as_uint(d) << 32) | (ull)(unsigned)p;
    lmin = (key[j] < lmin) ? key[j] : lmin;
  }

  __shared__ ull wred[2][KNN_W];  // parity-double-buffered per-wave minima
  __shared__ int widx[GS];

  for (int k = 0; k < GS; ++k) {
    int kb = k & 1;
    ull v = lmin;
    // wave-level min via DPP (VALU only): row_shr 1/2/4/8, bcast 15/31
    v = dpp_min64<0x111>(v);
    v = dpp_min64<0x112>(v);
    v = dpp_min64<0x114>(v);
    v = dpp_min64<0x118>(v);
    v = dpp_min64<0x142>(v);
    v = dpp_min64<0x143>(v);
    unsigned vlo = (unsigned)__builtin_amdgcn_readlane((int)(unsigned)v, 63);
    unsigned vhi = (unsigned)__builtin_amdgcn_readlane((int)(unsigned)(v >> 32), 63);
    ull wv = ((ull)vhi << 32) | vlo;

    if ((t & 63) == 0) wred[kb][t >> 6] = wv;
    __syncthreads();

    ull gm = wred[kb][0];
#pragma unroll
    for (int w = 1; w < KNN_W; ++w) {
      ull o = wred[kb][w];
      gm = (o < gm) ? o : gm;
    }
    int idx = (int)(unsigned)gm;

    // only the owning lane rescans its keys (cached local min elsewhere)
    if (t == (idx & (KNN_T - 1))) {
      int jj = idx / KNN_T;
#pragma unroll
      for (int j = 0; j < KNN_P; ++j)
        if (j == jj) key[j] = ~0ull;
      lmin = ~0ull;
#pragma unroll
      for (int j = 0; j < KNN_P; ++j) lmin = (key[j] < lmin) ? key[j] : lmin;
    }
    if (t == 0) widx[k] = idx;
    // no second barrier: next round writes wred[(k+1)&1] (other buffer);
    // wred[kb] can't be overwritten before all waves read it (barrier k+1
    // can't complete until every wave has passed its wred[kb] read).
  }
  __syncthreads();  // widx fully written

  // gather & write neighborhood (B, NG, GS, 3), k ascending by (d, idx)
  if (t < GS) {
    int idx = widx[t];
    int o = ((b * NG + g) * GS + t) * 3;
    out[o + 0] = bx[idx];
    out[o + 1] = by[idx];
    out[o + 2] = bz[idx];
  }
}

extern "C" void kernel_launch(void* const* d_in, const int* in_sizes, int n_in,
                              void* d_out, int out_size, void* d_ws, size_t ws_size,
                              hipStream_t stream) {
  const float* xyz = (const float*)d_in[0];   // (B, N, 3) f32
  const float* pose = (const float*)d_in[1];  // (B, 3, 4) f32
  float* out = (float*)d_out;                 // neighborhood (B,NG,GS,3) ++ center (B,NG,3)

  float* xs = (float*)d_ws;       // SoA transformed points
  float* ys = xs + B * N;
  float* zs = ys + B * N;
  float* centers = out + B * NG * GS * 3;  // center block of d_out

  transform_k<<<dim3((B * N + 255) / 256), dim3(256), 0, stream>>>(xyz, pose, xs, ys, zs);
  fps_k<<<dim3(B), dim3(FPS_T), 0, stream>>>(xs, ys, zs, centers);
  knn_k<<<dim3(NG, B), dim3(KNN_T), 0, stream>>>(xs, ys, zs, centers, out);
}

// Round 12
// 1479.835 us; speedup vs baseline: 2.0858x; 2.0858x over previous
//
#include <hip/hip_runtime.h>
#include <stdint.h>

#define B 8
#define N 8192
#define NG 512
#define GS 32

typedef unsigned long long ull;

// Exact (no-FMA, left-to-right) squared distance: ((dx*dx + dy*dy) + dz*dz)
__device__ __forceinline__ float sq3(float dx, float dy, float dz) {
#pragma clang fp contract(off)
  return dx * dx + dy * dy + dz * dz;
}

// ---- DPP reduction helpers (pure VALU). Chain 0x111,0x112,0x114,0x118,
// 0x142,0x143 leaves the full-wave result in lane 63 (validated R2-R11).
template <int CTRL>
__device__ __forceinline__ float dpp_maxf(float x) {
  float o = __int_as_float(__builtin_amdgcn_update_dpp(
      __float_as_int(x), __float_as_int(x), CTRL, 0xf, 0xf, false));
  return fmaxf(x, o);
}
template <int CTRL>
__device__ __forceinline__ float dpp_minf(float x) {
  float o = __int_as_float(__builtin_amdgcn_update_dpp(
      __float_as_int(x), __float_as_int(x), CTRL, 0xf, 0xf, false));
  return fminf(x, o);
}
template <int CTRL>
__device__ __forceinline__ ull dpp_max64(ull key) {
  unsigned lo = (unsigned)key, hi = (unsigned)(key >> 32);
  unsigned olo = (unsigned)__builtin_amdgcn_update_dpp((int)lo, (int)lo, CTRL, 0xf, 0xf, false);
  unsigned ohi = (unsigned)__builtin_amdgcn_update_dpp((int)hi, (int)hi, CTRL, 0xf, 0xf, false);
  ull o = ((ull)ohi << 32) | olo;
  return (o > key) ? o : key;
}
template <int CTRL>
__device__ __forceinline__ ull dpp_min64(ull key) {
  unsigned lo = (unsigned)key, hi = (unsigned)(key >> 32);
  unsigned olo = (unsigned)__builtin_amdgcn_update_dpp((int)lo, (int)lo, CTRL, 0xf, 0xf, false);
  unsigned ohi = (unsigned)__builtin_amdgcn_update_dpp((int)hi, (int)hi, CTRL, 0xf, 0xf, false);
  ull o = ((ull)ohi << 32) | olo;
  return (o < key) ? o : key;
}

__device__ __forceinline__ float wave_max_f(float x) {
  x = dpp_maxf<0x111>(x); x = dpp_maxf<0x112>(x); x = dpp_maxf<0x114>(x);
  x = dpp_maxf<0x118>(x); x = dpp_maxf<0x142>(x); x = dpp_maxf<0x143>(x);
  return __int_as_float(__builtin_amdgcn_readlane(__float_as_int(x), 63));
}
__device__ __forceinline__ float wave_min_f(float x) {
  x = dpp_minf<0x111>(x); x = dpp_minf<0x112>(x); x = dpp_minf<0x114>(x);
  x = dpp_minf<0x118>(x); x = dpp_minf<0x142>(x); x = dpp_minf<0x143>(x);
  return __int_as_float(__builtin_amdgcn_readlane(__float_as_int(x), 63));
}

// 3-bit Morton spread: bits -> positions 0,3,6
__device__ __forceinline__ unsigned exp3(unsigned v) {
  return (v & 1u) | ((v & 2u) << 2) | ((v & 4u) << 4);
}

// ---------------- Kernel 1: SE(3) transform, AoS xyz -> SoA xs/ys/zs ------
__global__ void transform_k(const float* __restrict__ xyz,
                            const float* __restrict__ pose,
                            float* __restrict__ xs, float* __restrict__ ys,
                            float* __restrict__ zs) {
#pragma clang fp contract(off)
  int i = blockIdx.x * blockDim.x + threadIdx.x;
  if (i >= B * N) return;
  int b = i / N;
  const float* P = pose + b * 12;  // (3,4) row-major: R|t
  float p0 = xyz[i * 3 + 0], p1 = xyz[i * 3 + 1], p2 = xyz[i * 3 + 2];
  float ox = ((P[0] * p0 + P[1] * p1) + P[2] * p2) + P[3];
  float oy = ((P[4] * p0 + P[5] * p1) + P[6] * p2) + P[7];
  float oz = ((P[8] * p0 + P[9] * p1) + P[10] * p2) + P[11];
  xs[i] = ox;
  ys[i] = oy;
  zs[i] = oz;
}

// ---------------- Kernel 2: bucket-skip FPS (exact), 1 block per batch ----
// Morton-sorted points in LDS, 128 chunks x 64 points with tight bboxes.
// Skip rule: 0.9999f*dmin_box^2 >= chunk_maxdist  =>  for every member
// d(i,c) >= dmin >= max >= dist[i], so min(dist,d)==dist BIT-EXACTLY.
// (fp safety: both sides carry <=~1e-6 relative rounding; the 1e-4 margin
// dominates, so the skip can never fire when any true update could occur.)
// Skipped chunks carry cached (maxdist, min-orig-idx, coords) forward.
// Selection key = (distbits<<32)|(8191-origidx): global u64-max == reference
// (max dist, first/min index). Orig indices ride through the sort, so the
// nondeterministic atomic scatter order cannot affect any output bit.
// One barrier/step: parity-double-buffered chunk state with copy-forward.
#define FT 256
#define NWV 4
#define NC 128

__global__ __launch_bounds__(FT) void fps_k(const float* __restrict__ xs,
                                            const float* __restrict__ ys,
                                            const float* __restrict__ zs,
                                            float* __restrict__ centers) {
#pragma clang fp contract(off)
  int b = blockIdx.x, t = threadIdx.x;
  int lane = t & 63, w = t >> 6;

  __shared__ float sX[N], sY[N], sZ[N];        // sorted points (96 KB)
  __shared__ float sD[N];                      // dist array (32 KB)
  __shared__ unsigned short sI[N];             // orig index (16 KB)
  __shared__ float blx[NC], bly[NC], blz[NC];  // chunk bbox lo
  __shared__ float bhx[NC], bhy[NC], bhz[NC];  // chunk bbox hi
  __shared__ ull ckey[2][NC];                  // parity chunk keys
  __shared__ float cwx[2][NC], cwy[2][NC], cwz[2][NC];  // parity winner coords
  __shared__ unsigned hist[512];               // cell histogram / cursors
  __shared__ float bbr[NWV * 6];               // bbox wave partials

  const float* __restrict__ bx = xs + b * N;
  const float* __restrict__ by = ys + b * N;
  const float* __restrict__ bz = zs + b * N;

  // ---- pass 0: global bbox (wave partials -> all-thread combine)
  float mnx = 3.0e38f, mny = 3.0e38f, mnz = 3.0e38f;
  float mxx = -3.0e38f, mxy = -3.0e38f, mxz = -3.0e38f;
  for (int i = t; i < N; i += FT) {
    float x = bx[i], y = by[i], z = bz[i];
    mnx = fminf(mnx, x); mxx = fmaxf(mxx, x);
    mny = fminf(mny, y); mxy = fmaxf(mxy, y);
    mnz = fminf(mnz, z); mxz = fmaxf(mxz, z);
  }
  mnx = wave_min_f(mnx); mny = wave_min_f(mny); mnz = wave_min_f(mnz);
  mxx = wave_max_f(mxx); mxy = wave_max_f(mxy); mxz = wave_max_f(mxz);
  if (lane == 0) {
    bbr[w * 6 + 0] = mnx; bbr[w * 6 + 1] = mny; bbr[w * 6 + 2] = mnz;
    bbr[w * 6 + 3] = mxx; bbr[w * 6 + 4] = mxy; bbr[w * 6 + 5] = mxz;
  }
  hist[t] = 0u;
  hist[t + 256] = 0u;
  __syncthreads();
  mnx = fminf(fminf(bbr[0], bbr[6]), fminf(bbr[12], bbr[18]));
  mny = fminf(fminf(bbr[1], bbr[7]), fminf(bbr[13], bbr[19]));
  mnz = fminf(fminf(bbr[2], bbr[8]), fminf(bbr[14], bbr[20]));
  mxx = fmaxf(fmaxf(bbr[3], bbr[9]), fmaxf(bbr[15], bbr[21]));
  mxy = fmaxf(fmaxf(bbr[4], bbr[10]), fmaxf(bbr[16], bbr[22]));
  mxz = fmaxf(fmaxf(bbr[5], bbr[11]), fmaxf(bbr[17], bbr[23]));
  float ex = mxx - mnx, ey = mxy - mny, ez = mxz - mnz;
  float qsx = ex > 0.f ? 8.0f / ex : 0.f;
  float qsy = ey > 0.f ? 8.0f / ey : 0.f;
  float qsz = ez > 0.f ? 8.0f / ez : 0.f;

  // ---- pass 1: Morton-9 cell histogram
  for (int i = t; i < N; i += FT) {
    float x = bx[i], y = by[i], z = bz[i];
    int qx = (int)((x - mnx) * qsx); qx = qx < 0 ? 0 : (qx > 7 ? 7 : qx);
    int qy = (int)((y - mny) * qsy); qy = qy < 0 ? 0 : (qy > 7 ? 7 : qy);
    int qz = (int)((z - mnz) * qsz); qz = qz < 0 ? 0 : (qz > 7 ? 7 : qz);
    unsigned cell = exp3((unsigned)qx) | (exp3((unsigned)qy) << 1) | (exp3((unsigned)qz) << 2);
    atomicAdd(&hist[cell], 1u);
  }
  __syncthreads();

  // ---- pass 2: exclusive scan of hist[512] (wave 0: 8 bins/lane + shfl_up)
  if (w == 0) {
    unsigned v[8];
    unsigned base = (unsigned)lane * 8u;
    unsigned s = 0;
    for (int j = 0; j < 8; ++j) v[j] = hist[base + j];
    for (int j = 0; j < 8; ++j) { unsigned tmp = v[j]; v[j] = s; s += tmp; }
    unsigned run = s;
    for (int off = 1; off < 64; off <<= 1) {
      unsigned o = __shfl_up(run, off, 64);
      if (lane >= off) run += o;
    }
    unsigned excl = run - s;
    for (int j = 0; j < 8; ++j) hist[base + j] = v[j] + excl;
  }
  __syncthreads();

  // ---- pass 3: scatter into sorted order (+ dist init, orig idx)
  for (int i = t; i < N; i += FT) {
    float x = bx[i], y = by[i], z = bz[i];
    int qx = (int)((x - mnx) * qsx); qx = qx < 0 ? 0 : (qx > 7 ? 7 : qx);
    int qy = (int)((y - mny) * qsy); qy = qy < 0 ? 0 : (qy > 7 ? 7 : qy);
    int qz = (int)((z - mnz) * qsz); qz = qz < 0 ? 0 : (qz > 7 ? 7 : qz);
    unsigned cell = exp3((unsigned)qx) | (exp3((unsigned)qy) << 1) | (exp3((unsigned)qz) << 2);
    unsigned pos = atomicAdd(&hist[cell], 1u);
    sX[pos] = x; sY[pos] = y; sZ[pos] = z;
    sI[pos] = (unsigned short)i;
    sD[pos] = 1e10f;  // matches jnp.full(..., 1e10, f32)
  }
  __syncthreads();

  // ---- pass 4: chunk bboxes + initial chunk keys (maxdist = 1e10)
  for (int c = w; c < NC; c += NWV) {
    int p = (c << 6) + lane;
    float x = sX[p], y = sY[p], z = sZ[p];
    float l0 = wave_min_f(x), h0 = wave_max_f(x);
    float l1 = wave_min_f(y), h1 = wave_max_f(y);
    float l2 = wave_min_f(z), h2 = wave_max_f(z);
    if (lane == 0) {
      blx[c] = l0; bly[c] = l1; blz[c] = l2;
      bhx[c] = h0; bhy[c] = h1; bhz[c] = h2;
      ckey[0][c] = ((ull)__float_as_uint(1e10f)) << 32;
    }
  }
  float lx = bx[0], ly = by[0], lz = bz[0];  // first center = orig point 0
  __syncthreads();

  // ---- main loop: one barrier per step
  for (int k = 0; k < NG; ++k) {
    if (t == 0) {  // emit 'last' BEFORE update (scan output order)
      int o = (b * NG + k) * 3;
      centers[o + 0] = lx;
      centers[o + 1] = ly;
      centers[o + 2] = lz;
    }
    int pr = k & 1, npr = pr ^ 1;

    // skip test + state copy-forward. Lane l (<32) owns chunk c = l*4 + w
    // (interleaved: Morton-adjacent chunks go to different waves).
    bool doscan = false;
    if (lane < 32) {
      int c = (lane << 2) + w;
      float gx = fmaxf(fmaxf(blx[c] - lx, lx - bhx[c]), 0.0f);
      float gy = fmaxf(fmaxf(bly[c] - ly, ly - bhy[c]), 0.0f);
      float gz = fmaxf(fmaxf(blz[c] - lz, lz - bhz[c]), 0.0f);
      float dmin = sq3(gx, gy, gz);
      ull oldk = ckey[pr][c];
      float omax = __uint_as_float((unsigned)(oldk >> 32));
      doscan = !(dmin * 0.9999f >= omax);
      // copy state to new parity (scan overwrites later in program order)
      ckey[npr][c] = oldk;
      cwx[npr][c] = cwx[pr][c];
      cwy[npr][c] = cwy[pr][c];
      cwz[npr][c] = cwz[pr][c];
    }
    unsigned mask = (unsigned)__ballot(doscan);  // bits 0..31, wave-uniform

    while (mask) {
      int l = __ffs(mask) - 1;
      mask &= mask - 1;
      int c = (l << 2) + w;
      int p = (c << 6) + lane;
      float x = sX[p], y = sY[p], z = sZ[p];
      int oi = sI[p];
      float dx = x - lx, dy = y - ly, dz = z - lz;
      float d = (dx * dx + dy * dy) + dz * dz;  // exact reference order
      float dm = fminf(sD[p], d);
      sD[p] = dm;
      // wave argmax, exact tie -> min ORIGINAL index
      float wm = dm;
      wm = dpp_maxf<0x111>(wm); wm = dpp_maxf<0x112>(wm); wm = dpp_maxf<0x114>(wm);
      wm = dpp_maxf<0x118>(wm); wm = dpp_maxf<0x142>(wm); wm = dpp_maxf<0x143>(wm);
      float wmax = __int_as_float(__builtin_amdgcn_readlane(__float_as_int(wm), 63));
      ull m2 = __ballot(dm == wmax);
      unsigned besto = 0xffffffffu;
      int wl = 0;
      while (m2) {  // wave-uniform; almost always 1 iteration
        int l2 = (int)(__ffsll(m2) - 1);
        m2 &= m2 - 1;
        unsigned o2 = (unsigned)__builtin_amdgcn_readlane(oi, l2);
        if (o2 < besto) { besto = o2; wl = l2; }
      }
      if (lane == wl) {
        ckey[npr][c] =
            (((ull)__float_as_uint(wmax)) << 32) | (ull)(unsigned)(N - 1 - (int)besto);
        cwx[npr][c] = x;
        cwy[npr][c] = y;
        cwz[npr][c] = z;
      }
    }
    __syncthreads();

    // global argmax over 128 chunk keys (redundant per wave; keys unique
    // because orig indices are unique -> exactly one matching chunk).
    ull k1 = ckey[npr][lane];
    ull k2 = ckey[npr][64 + lane];
    ull km = (k2 > k1) ? k2 : k1;
    km = dpp_max64<0x111>(km); km = dpp_max64<0x112>(km); km = dpp_max64<0x114>(km);
    km = dpp_max64<0x118>(km); km = dpp_max64<0x142>(km); km = dpp_max64<0x143>(km);
    unsigned klo = (unsigned)__builtin_amdgcn_readlane((int)(unsigned)km, 63);
    unsigned khi = (unsigned)__builtin_amdgcn_readlane((int)(unsigned)(km >> 32), 63);
    ull wk = ((ull)khi << 32) | klo;
    ull b1 = __ballot(k1 == wk);
    ull b2 = __ballot(k2 == wk);
    int c = b1 ? (int)(__ffsll(b1) - 1) : (64 + (int)(__ffsll(b2) - 1));
    lx = cwx[npr][c];
    ly = cwy[npr][c];
    lz = cwz[npr][c];
    // no second barrier: next step reads parity npr (stable) and writes
    // parity pr, which no wave still reads; sD regions are wave-disjoint.
  }
}

// ---------------- Kernel 3: exact 32-NN per center, 1 block per center ----
// DPP (VALU) u64-min wave reduction + parity-double-buffered partials:
// ONE barrier per extraction round (plus one final before the gather).
#define KNN_T 256
#define KNN_W (KNN_T / 64)
#define KNN_P (N / KNN_T)  // 32 points per thread

__global__ __launch_bounds__(KNN_T, 2) void knn_k(const float* __restrict__ xs,
                                                  const float* __restrict__ ys,
                                                  const float* __restrict__ zs,
                                                  const float* __restrict__ centers,
                                                  float* __restrict__ out) {
#pragma clang fp contract(off)
  int b = blockIdx.y, g = blockIdx.x, t = threadIdx.x;
  const float* bx = xs + b * N;
  const float* by = ys + b * N;
  const float* bz = zs + b * N;
  int ci = (b * NG + g) * 3;
  float cx = centers[ci], cy = centers[ci + 1], cz = centers[ci + 2];

  // packed keys: (distBits<<32)|idx ; min over key == min dist, tie -> min idx
  ull key[KNN_P];
  ull lmin = ~0ull;
#pragma unroll
  for (int j = 0; j < KNN_P; ++j) {
    int p = j * KNN_T + t;
    float dx = bx[p] - cx, dy = by[p] - cy, dz = bz[p] - cz;
    float d = sq3(dx, dy, dz);
    key[j] = ((ull)__float_as_uint(d) << 32) | (ull)(unsigned)p;
    lmin = (key[j] < lmin) ? key[j] : lmin;
  }

  __shared__ ull wred[2][KNN_W];  // parity-double-buffered per-wave minima
  __shared__ int widx[GS];

  for (int k = 0; k < GS; ++k) {
    int kb = k & 1;
    ull v = lmin;
    v = dpp_min64<0x111>(v);
    v = dpp_min64<0x112>(v);
    v = dpp_min64<0x114>(v);
    v = dpp_min64<0x118>(v);
    v = dpp_min64<0x142>(v);
    v = dpp_min64<0x143>(v);
    unsigned vlo = (unsigned)__builtin_amdgcn_readlane((int)(unsigned)v, 63);
    unsigned vhi = (unsigned)__builtin_amdgcn_readlane((int)(unsigned)(v >> 32), 63);
    ull wv = ((ull)vhi << 32) | vlo;

    if ((t & 63) == 0) wred[kb][t >> 6] = wv;
    __syncthreads();

    ull gm = wred[kb][0];
#pragma unroll
    for (int w = 1; w < KNN_W; ++w) {
      ull o = wred[kb][w];
      gm = (o < gm) ? o : gm;
    }
    int idx = (int)(unsigned)gm;

    // only the owning lane rescans its keys (cached local min elsewhere)
    if (t == (idx & (KNN_T - 1))) {
      int jj = idx / KNN_T;
#pragma unroll
      for (int j = 0; j < KNN_P; ++j)
        if (j == jj) key[j] = ~0ull;
      lmin = ~0ull;
#pragma unroll
      for (int j = 0; j < KNN_P; ++j) lmin = (key[j] < lmin) ? key[j] : lmin;
    }
    if (t == 0) widx[k] = idx;
    // no second barrier: next round writes wred[(k+1)&1] (other buffer)
  }
  __syncthreads();  // widx fully written

  // gather & write neighborhood (B, NG, GS, 3), k ascending by (d, idx)
  if (t < GS) {
    int idx = widx[t];
    int o = ((b * NG + g) * GS + t) * 3;
    out[o + 0] = bx[idx];
    out[o + 1] = by[idx];
    out[o + 2] = bz[idx];
  }
}

extern "C" void kernel_launch(void* const* d_in, const int* in_sizes, int n_in,
                              void* d_out, int out_size, void* d_ws, size_t ws_size,
                              hipStream_t stream) {
  const float* xyz = (const float*)d_in[0];   // (B, N, 3) f32
  const float* pose = (const float*)d_in[1];  // (B, 3, 4) f32
  float* out = (float*)d_out;                 // neighborhood (B,NG,GS,3) ++ center (B,NG,3)

  float* xs = (float*)d_ws;       // SoA transformed points
  float* ys = xs + B * N;
  float* zs = ys + B * N;
  float* centers = out + B * NG * GS * 3;  // center block of d_out

  transform_k<<<dim3((B * N + 255) / 256), dim3(256), 0, stream>>>(xyz, pose, xs, ys, zs);
  fps_k<<<dim3(B), dim3(FT), 0, stream>>>(xs, ys, zs, centers);
  knn_k<<<dim3(NG, B), dim3(KNN_T), 0, stream>>>(xs, ys, zs, centers, out);
}

// Round 13
// 1215.503 us; speedup vs baseline: 2.5394x; 1.2175x over previous
//
#include <hip/hip_runtime.h>
#include <hip/hip_fp16.h>
#include <stdint.h>

#define B 8
#define N 8192
#define NG 512
#define GS 32

typedef unsigned long long ull;

// Exact (no-FMA, left-to-right) squared distance: ((dx*dx + dy*dy) + dz*dz)
__device__ __forceinline__ float sq3(float dx, float dy, float dz) {
#pragma clang fp contract(off)
  return dx * dx + dy * dy + dz * dz;
}

// ---- DPP reduction helpers (pure VALU). row_shr 1/2/4/8 reduce within each
// 16-lane row (result in lane 15 of the row); adding 0x142,0x143 extends to
// the full wave (result in lane 63). Validated R2-R12 (absmax stayed 0.0).
template <int CTRL>
__device__ __forceinline__ float dpp_maxf(float x) {
  float o = __int_as_float(__builtin_amdgcn_update_dpp(
      __float_as_int(x), __float_as_int(x), CTRL, 0xf, 0xf, false));
  return fmaxf(x, o);
}
template <int CTRL>
__device__ __forceinline__ float dpp_minf(float x) {
  float o = __int_as_float(__builtin_amdgcn_update_dpp(
      __float_as_int(x), __float_as_int(x), CTRL, 0xf, 0xf, false));
  return fminf(x, o);
}
template <int CTRL>
__device__ __forceinline__ ull dpp_max64(ull key) {
  unsigned lo = (unsigned)key, hi = (unsigned)(key >> 32);
  unsigned olo = (unsigned)__builtin_amdgcn_update_dpp((int)lo, (int)lo, CTRL, 0xf, 0xf, false);
  unsigned ohi = (unsigned)__builtin_amdgcn_update_dpp((int)hi, (int)hi, CTRL, 0xf, 0xf, false);
  ull o = ((ull)ohi << 32) | olo;
  return (o > key) ? o : key;
}
template <int CTRL>
__device__ __forceinline__ ull dpp_min64(ull key) {
  unsigned lo = (unsigned)key, hi = (unsigned)(key >> 32);
  unsigned olo = (unsigned)__builtin_amdgcn_update_dpp((int)lo, (int)lo, CTRL, 0xf, 0xf, false);
  unsigned ohi = (unsigned)__builtin_amdgcn_update_dpp((int)hi, (int)hi, CTRL, 0xf, 0xf, false);
  ull o = ((ull)ohi << 32) | olo;
  return (o < key) ? o : key;
}

__device__ __forceinline__ float wave_max_f(float x) {
  x = dpp_maxf<0x111>(x); x = dpp_maxf<0x112>(x); x = dpp_maxf<0x114>(x);
  x = dpp_maxf<0x118>(x); x = dpp_maxf<0x142>(x); x = dpp_maxf<0x143>(x);
  return __int_as_float(__builtin_amdgcn_readlane(__float_as_int(x), 63));
}
__device__ __forceinline__ float wave_min_f(float x) {
  x = dpp_minf<0x111>(x); x = dpp_minf<0x112>(x); x = dpp_minf<0x114>(x);
  x = dpp_minf<0x118>(x); x = dpp_minf<0x142>(x); x = dpp_minf<0x143>(x);
  return __int_as_float(__builtin_amdgcn_readlane(__float_as_int(x), 63));
}

// 3-bit Morton spread: bits -> positions 0,3,6
__device__ __forceinline__ unsigned exp3(unsigned v) {
  return (v & 1u) | ((v & 2u) << 2) | ((v & 4u) << 4);
}

// conservative f16 bbox encode: pad 0.02 >> f16 rn error for |v| < 16
__device__ __forceinline__ unsigned short f16lo(float v) {
  return __half_as_ushort(__float2half(v - 0.02f));
}
__device__ __forceinline__ unsigned short f16hi(float v) {
  return __half_as_ushort(__float2half(v + 0.02f));
}

// ---------------- Kernel 1: SE(3) transform, AoS xyz -> SoA xs/ys/zs ------
__global__ void transform_k(const float* __restrict__ xyz,
                            const float* __restrict__ pose,
                            float* __restrict__ xs, float* __restrict__ ys,
                            float* __restrict__ zs) {
#pragma clang fp contract(off)
  int i = blockIdx.x * blockDim.x + threadIdx.x;
  if (i >= B * N) return;
  int b = i / N;
  const float* P = pose + b * 12;  // (3,4) row-major: R|t
  float p0 = xyz[i * 3 + 0], p1 = xyz[i * 3 + 1], p2 = xyz[i * 3 + 2];
  float ox = ((P[0] * p0 + P[1] * p1) + P[2] * p2) + P[3];
  float oy = ((P[4] * p0 + P[5] * p1) + P[6] * p2) + P[7];
  float oz = ((P[8] * p0 + P[9] * p1) + P[10] * p2) + P[11];
  xs[i] = ox;
  ys[i] = oy;
  zs[i] = oz;
}

// ---------------- Kernel 2: bucket-skip FPS v2 (exact), 1 block/batch -----
// R13: 512 chunks x 16 points; per wave-iteration, 4 chunks are scanned in
// parallel (one per 16-lane row) with a 4-stage row-local DPP64 argmax —
// no ballot/readlane in the loop (R12's ~400cyc/chunk serial chain -> ~150
// cyc per 4 chunks). Tie-break packed in the key:
//   key = distbits<<32 | (8191-origidx)<<9 | chunk   (origidx unique)
// u64-max == (max dist, min orig idx) == reference argmax semantics.
// Skip rule (exact cached chunk max): 0.9999*dmin_paddedbox >= cached_max
// => every member's reference min(dist,d)==dist bit-exactly (pad 0.02 +
// 1e-4 margin dominate all fp rounding). Chunk state is owner-major
// (wave w's 128 chunks contiguous) -> conflict-free strides; no cross-wave
// state reads pre-barrier (per-wave key published to parity wkey).
// Atomic-scatter nondeterminism cannot affect output: dist updates and the
// global (dist, origidx) key order are partition-independent.
#define FT 256
#define NC 512
#define CPW (NC / 4)  // 128 chunks per wave

__global__ __launch_bounds__(FT) void fps_k(const float* __restrict__ xs,
                                            const float* __restrict__ ys,
                                            const float* __restrict__ zs,
                                            float* __restrict__ centers) {
#pragma clang fp contract(off)
  int b = blockIdx.x, t = threadIdx.x;
  int lane = t & 63, w = t >> 6;

  __shared__ float sX[N], sY[N], sZ[N];   // sorted points (96 KB)
  __shared__ float sD[N];                 // dist array (32 KB)
  __shared__ unsigned short sI[N];        // sorted pos -> orig idx (16 KB)
  __shared__ ull ckey[NC];                // per-chunk cached key (owner-major)
  __shared__ unsigned short bbl[3][NC];   // f16 bbox lo (owner-major)
  __shared__ unsigned short bbh[3][NC];   // f16 bbox hi
  __shared__ unsigned hist[512];          // cell histogram / scatter cursors
  __shared__ float bbr[4 * 6];            // global-bbox wave partials
  __shared__ ull wkey[2][4];              // parity per-wave winner keys

  const float* __restrict__ bx = xs + b * N;
  const float* __restrict__ by = ys + b * N;
  const float* __restrict__ bz = zs + b * N;

  // ---- pass 0: global bbox
  float mnx = 3.0e38f, mny = 3.0e38f, mnz = 3.0e38f;
  float mxx = -3.0e38f, mxy = -3.0e38f, mxz = -3.0e38f;
  for (int i = t; i < N; i += FT) {
    float x = bx[i], y = by[i], z = bz[i];
    mnx = fminf(mnx, x); mxx = fmaxf(mxx, x);
    mny = fminf(mny, y); mxy = fmaxf(mxy, y);
    mnz = fminf(mnz, z); mxz = fmaxf(mxz, z);
  }
  mnx = wave_min_f(mnx); mny = wave_min_f(mny); mnz = wave_min_f(mnz);
  mxx = wave_max_f(mxx); mxy = wave_max_f(mxy); mxz = wave_max_f(mxz);
  if (lane == 0) {
    bbr[w * 6 + 0] = mnx; bbr[w * 6 + 1] = mny; bbr[w * 6 + 2] = mnz;
    bbr[w * 6 + 3] = mxx; bbr[w * 6 + 4] = mxy; bbr[w * 6 + 5] = mxz;
  }
  hist[t] = 0u;
  hist[t + 256] = 0u;
  __syncthreads();
  mnx = fminf(fminf(bbr[0], bbr[6]), fminf(bbr[12], bbr[18]));
  mny = fminf(fminf(bbr[1], bbr[7]), fminf(bbr[13], bbr[19]));
  mnz = fminf(fminf(bbr[2], bbr[8]), fminf(bbr[14], bbr[20]));
  mxx = fmaxf(fmaxf(bbr[3], bbr[9]), fmaxf(bbr[15], bbr[21]));
  mxy = fmaxf(fmaxf(bbr[4], bbr[10]), fmaxf(bbr[16], bbr[22]));
  mxz = fmaxf(fmaxf(bbr[5], bbr[11]), fmaxf(bbr[17], bbr[23]));
  float ex = mxx - mnx, ey = mxy - mny, ez = mxz - mnz;
  float qsx = ex > 0.f ? 8.0f / ex : 0.f;
  float qsy = ey > 0.f ? 8.0f / ey : 0.f;
  float qsz = ez > 0.f ? 8.0f / ez : 0.f;

  // ---- pass 1: Morton-9 cell histogram
  for (int i = t; i < N; i += FT) {
    float x = bx[i], y = by[i], z = bz[i];
    int qx = (int)((x - mnx) * qsx); qx = qx < 0 ? 0 : (qx > 7 ? 7 : qx);
    int qy = (int)((y - mny) * qsy); qy = qy < 0 ? 0 : (qy > 7 ? 7 : qy);
    int qz = (int)((z - mnz) * qsz); qz = qz < 0 ? 0 : (qz > 7 ? 7 : qz);
    unsigned cell = exp3((unsigned)qx) | (exp3((unsigned)qy) << 1) | (exp3((unsigned)qz) << 2);
    atomicAdd(&hist[cell], 1u);
  }
  __syncthreads();

  // ---- pass 2: exclusive scan of hist[512] (wave 0)
  if (w == 0) {
    unsigned v[8];
    unsigned base = (unsigned)lane * 8u;
    unsigned s = 0;
    for (int j = 0; j < 8; ++j) v[j] = hist[base + j];
    for (int j = 0; j < 8; ++j) { unsigned tmp = v[j]; v[j] = s; s += tmp; }
    unsigned run = s;
    for (int off = 1; off < 64; off <<= 1) {
      unsigned o = __shfl_up(run, off, 64);
      if (lane >= off) run += o;
    }
    unsigned excl = run - s;
    for (int j = 0; j < 8; ++j) hist[base + j] = v[j] + excl;
  }
  __syncthreads();

  // ---- pass 3: scatter into sorted order (+ dist init, orig idx)
  for (int i = t; i < N; i += FT) {
    float x = bx[i], y = by[i], z = bz[i];
    int qx = (int)((x - mnx) * qsx); qx = qx < 0 ? 0 : (qx > 7 ? 7 : qx);
    int qy = (int)((y - mny) * qsy); qy = qy < 0 ? 0 : (qy > 7 ? 7 : qy);
    int qz = (int)((z - mnz) * qsz); qz = qz < 0 ? 0 : (qz > 7 ? 7 : qz);
    unsigned cell = exp3((unsigned)qx) | (exp3((unsigned)qy) << 1) | (exp3((unsigned)qz) << 2);
    unsigned pos = atomicAdd(&hist[cell], 1u);
    sX[pos] = x; sY[pos] = y; sZ[pos] = z;
    sI[pos] = (unsigned short)i;
    sD[pos] = 1e10f;  // matches jnp.full(..., 1e10, f32)
  }
  __syncthreads();

  // ---- pass 4: chunk bboxes (4 chunks/iter, row-parallel) + ckey init
  // ownership: wave w owns logical chunks {c : c&3==w}, stored owner-major
  // at physical ph = w*CPW + (c>>2).
  for (int it = 0; it < CPW / 4; ++it) {
    int ph = w * CPW + it * 4 + (lane >> 4);
    int c = ((ph & (CPW - 1)) << 2) | w;  // logical chunk
    int p = (c << 4) + (lane & 15);
    float x = sX[p], y = sY[p], z = sZ[p];
    float l0 = x, h0 = x, l1 = y, h1 = y, l2 = z, h2 = z;
    l0 = dpp_minf<0x111>(l0); l0 = dpp_minf<0x112>(l0); l0 = dpp_minf<0x114>(l0); l0 = dpp_minf<0x118>(l0);
    h0 = dpp_maxf<0x111>(h0); h0 = dpp_maxf<0x112>(h0); h0 = dpp_maxf<0x114>(h0); h0 = dpp_maxf<0x118>(h0);
    l1 = dpp_minf<0x111>(l1); l1 = dpp_minf<0x112>(l1); l1 = dpp_minf<0x114>(l1); l1 = dpp_minf<0x118>(l1);
    h1 = dpp_maxf<0x111>(h1); h1 = dpp_maxf<0x112>(h1); h1 = dpp_maxf<0x114>(h1); h1 = dpp_maxf<0x118>(h1);
    l2 = dpp_minf<0x111>(l2); l2 = dpp_minf<0x112>(l2); l2 = dpp_minf<0x114>(l2); l2 = dpp_minf<0x118>(l2);
    h2 = dpp_maxf<0x111>(h2); h2 = dpp_maxf<0x112>(h2); h2 = dpp_maxf<0x114>(h2); h2 = dpp_maxf<0x118>(h2);
    if ((lane & 15) == 15) {
      bbl[0][ph] = f16lo(l0); bbh[0][ph] = f16hi(h0);
      bbl[1][ph] = f16lo(l1); bbh[1][ph] = f16hi(h1);
      bbl[2][ph] = f16lo(l2); bbh[2][ph] = f16hi(h2);
      ckey[ph] = ((ull)__float_as_uint(1e10f)) << 32;  // forces first scan
    }
  }
  float lx = bx[0], ly = by[0], lz = bz[0];  // first center = orig point 0
  __syncthreads();

  // ---- main loop: one barrier per step
  for (int k = 0; k < NG; ++k) {
    if (t == 0) {  // emit 'last' BEFORE update (scan output order)
      int o = (b * NG + k) * 3;
      centers[o + 0] = lx;
      centers[o + 1] = ly;
      centers[o + 2] = lz;
    }
    int par = k & 1;

    // skip test: lane handles owned chunks ph and ph+64 (conflict-free)
    ull m1, m2;
    {
      int ph = w * CPW + lane;
      bool a1, a2;
      {
        float lox = __half2float(__ushort_as_half(bbl[0][ph]));
        float loy = __half2float(__ushort_as_half(bbl[1][ph]));
        float loz = __half2float(__ushort_as_half(bbl[2][ph]));
        float hix = __half2float(__ushort_as_half(bbh[0][ph]));
        float hiy = __half2float(__ushort_as_half(bbh[1][ph]));
        float hiz = __half2float(__ushort_as_half(bbh[2][ph]));
        float gx = fmaxf(fmaxf(lox - lx, lx - hix), 0.0f);
        float gy = fmaxf(fmaxf(loy - ly, ly - hiy), 0.0f);
        float gz = fmaxf(fmaxf(loz - lz, lz - hiz), 0.0f);
        float dmin = sq3(gx, gy, gz);
        float omax = __uint_as_float((unsigned)(ckey[ph] >> 32));
        a1 = !(dmin * 0.9999f >= omax);
      }
      {
        int ph2 = ph + 64;
        float lox = __half2float(__ushort_as_half(bbl[0][ph2]));
        float loy = __half2float(__ushort_as_half(bbl[1][ph2]));
        float loz = __half2float(__ushort_as_half(bbl[2][ph2]));
        float hix = __half2float(__ushort_as_half(bbh[0][ph2]));
        float hiy = __half2float(__ushort_as_half(bbh[1][ph2]));
        float hiz = __half2float(__ushort_as_half(bbh[2][ph2]));
        float gx = fmaxf(fmaxf(lox - lx, lx - hix), 0.0f);
        float gy = fmaxf(fmaxf(loy - ly, ly - hiy), 0.0f);
        float gz = fmaxf(fmaxf(loz - lz, lz - hiz), 0.0f);
        float dmin = sq3(gx, gy, gz);
        float omax = __uint_as_float((unsigned)(ckey[ph2] >> 32));
        a2 = !(dmin * 0.9999f >= omax);
      }
      m1 = __ballot(a1);
      m2 = __ballot(a2);
    }

    // scan loop: 4 active chunks per iteration (one per 16-lane row)
    int row = lane >> 4;
#pragma unroll 1
    for (int half = 0; half < 2; ++half) {
      ull m = half ? m2 : m1;
      int base = w * CPW + half * 64;
      while (m) {
        int c0 = __ffsll(m) - 1; m &= m - 1;
        int c1 = -1, c2 = -1, c3 = -1;
        if (m) { c1 = __ffsll(m) - 1; m &= m - 1; }
        if (m) { c2 = __ffsll(m) - 1; m &= m - 1; }
        if (m) { c3 = __ffsll(m) - 1; m &= m - 1; }
        int bit = (row == 0) ? c0 : (row == 1) ? c1 : (row == 2) ? c2 : c3;
        bool valid = bit >= 0;  // row-uniform
        ull kk = 0;
        int ph = 0;
        if (valid) {
          ph = base + bit;
          int c = ((ph & (CPW - 1)) << 2) | w;  // logical chunk
          int p = (c << 4) + (lane & 15);
          float x = sX[p], y = sY[p], z = sZ[p];
          float dx = x - lx, dy = y - ly, dz = z - lz;
          float d = (dx * dx + dy * dy) + dz * dz;  // exact reference order
          float dm = fminf(sD[p], d);
          sD[p] = dm;
          int oi = sI[p];
          kk = (((ull)__float_as_uint(dm)) << 32) |
               (((ull)(unsigned)(N - 1 - oi)) << 9) | (ull)(unsigned)c;
        }
        // row-local 4-stage DPP64 max: lane 15 of each row = chunk key
        kk = dpp_max64<0x111>(kk);
        kk = dpp_max64<0x112>(kk);
        kk = dpp_max64<0x114>(kk);
        kk = dpp_max64<0x118>(kk);
        if (valid && (lane & 15) == 15) ckey[ph] = kk;
      }
    }

    // per-wave argmax over its 128 owned ckeys (conflict-light strides)
    ull va = ckey[w * CPW + lane];
    ull vb = ckey[w * CPW + 64 + lane];
    ull vm = (vb > va) ? vb : va;
    vm = dpp_max64<0x111>(vm); vm = dpp_max64<0x112>(vm); vm = dpp_max64<0x114>(vm);
    vm = dpp_max64<0x118>(vm); vm = dpp_max64<0x142>(vm); vm = dpp_max64<0x143>(vm);
    unsigned klo = (unsigned)__builtin_amdgcn_readlane((int)(unsigned)vm, 63);
    unsigned khi = (unsigned)__builtin_amdgcn_readlane((int)(unsigned)(vm >> 32), 63);
    if (lane == 0) wkey[par][w] = ((ull)khi << 32) | klo;
    __syncthreads();

    // global merge (uniform reads) + winner decode from static arrays
    ull g0 = wkey[par][0], g1 = wkey[par][1], g2 = wkey[par][2], g3 = wkey[par][3];
    ull g = (g1 > g0) ? g1 : g0;
    ull h = (g3 > g2) ? g3 : g2;
    g = (h > g) ? h : g;
    int wc = (int)(g & 0x1FF);                       // winning logical chunk
    int oi = (N - 1) - (int)((g >> 9) & 0x1FFF);     // winning orig idx
    int pp = (wc << 4) + (lane & 15);
    ull bm = __ballot(sI[pp] == (unsigned short)oi);
    int hl = (int)(__ffsll(bm) - 1);
    int p = (wc << 4) + (hl & 15);
    lx = sX[p];  // uniform-address LDS broadcast reads
    ly = sY[p];
    lz = sZ[p];
    // no second barrier: next step's ckey writes are own-wave-only; wkey is
    // parity-buffered; sX/sY/sZ/sI are static after the sort.
  }
}

// ---------------- Kernel 3: exact 32-NN per center, 1 block per center ----
// DPP (VALU) u64-min wave reduction + parity-double-buffered partials:
// ONE barrier per extraction round (plus one final before the gather).
#define KNN_T 256
#define KNN_W (KNN_T / 64)
#define KNN_P (N / KNN_T)  // 32 points per thread

__global__ __launch_bounds__(KNN_T, 2) void knn_k(const float* __restrict__ xs,
                                                  const float* __restrict__ ys,
                                                  const float* __restrict__ zs,
                                                  const float* __restrict__ centers,
                                                  float* __restrict__ out) {
#pragma clang fp contract(off)
  int b = blockIdx.y, g = blockIdx.x, t = threadIdx.x;
  const float* bx = xs + b * N;
  const float* by = ys + b * N;
  const float* bz = zs + b * N;
  int ci = (b * NG + g) * 3;
  float cx = centers[ci], cy = centers[ci + 1], cz = centers[ci + 2];

  // packed keys: (distBits<<32)|idx ; min over key == min dist, tie -> min idx
  ull key[KNN_P];
  ull lmin = ~0ull;
#pragma unroll
  for (int j = 0; j < KNN_P; ++j) {
    int p = j * KNN_T + t;
    float dx = bx[p] - cx, dy = by[p] - cy, dz = bz[p] - cz;
    float d = sq3(dx, dy, dz);
    key[j] = ((ull)__float_as_uint(d) << 32) | (ull)(unsigned)p;
    lmin = (key[j] < lmin) ? key[j] : lmin;
  }

  __shared__ ull wred[2][KNN_W];  // parity-double-buffered per-wave minima
  __shared__ int widx[GS];

  for (int k = 0; k < GS; ++k) {
    int kb = k & 1;
    ull v = lmin;
    v = dpp_min64<0x111>(v);
    v = dpp_min64<0x112>(v);
    v = dpp_min64<0x114>(v);
    v = dpp_min64<0x118>(v);
    v = dpp_min64<0x142>(v);
    v = dpp_min64<0x143>(v);
    unsigned vlo = (unsigned)__builtin_amdgcn_readlane((int)(unsigned)v, 63);
    unsigned vhi = (unsigned)__builtin_amdgcn_readlane((int)(unsigned)(v >> 32), 63);
    ull wv = ((ull)vhi << 32) | vlo;

    if ((t & 63) == 0) wred[kb][t >> 6] = wv;
    __syncthreads();

    ull gm = wred[kb][0];
#pragma unroll
    for (int w = 1; w < KNN_W; ++w) {
      ull o = wred[kb][w];
      gm = (o < gm) ? o : gm;
    }
    int idx = (int)(unsigned)gm;

    // only the owning lane rescans its keys (cached local min elsewhere)
    if (t == (idx & (KNN_T - 1))) {
      int jj = idx / KNN_T;
#pragma unroll
      for (int j = 0; j < KNN_P; ++j)
        if (j == jj) key[j] = ~0ull;
      lmin = ~0ull;
#pragma unroll
      for (int j = 0; j < KNN_P; ++j) lmin = (key[j] < lmin) ? key[j] : lmin;
    }
    if (t == 0) widx[k] = idx;
    // no second barrier: next round writes wred[(k+1)&1] (other buffer)
  }
  __syncthreads();  // widx fully written

  // gather & write neighborhood (B, NG, GS, 3), k ascending by (d, idx)
  if (t < GS) {
    int idx = widx[t];
    int o = ((b * NG + g) * GS + t) * 3;
    out[o + 0] = bx[idx];
    out[o + 1] = by[idx];
    out[o + 2] = bz[idx];
  }
}

extern "C" void kernel_launch(void* const* d_in, const int* in_sizes, int n_in,
                              void* d_out, int out_size, void* d_ws, size_t ws_size,
                              hipStream_t stream) {
  const float* xyz = (const float*)d_in[0];   // (B, N, 3) f32
  const float* pose = (const float*)d_in[1];  // (B, 3, 4) f32
  float* out = (float*)d_out;                 // neighborhood (B,NG,GS,3) ++ center (B,NG,3)

  float* xs = (float*)d_ws;       // SoA transformed points
  float* ys = xs + B * N;
  float* zs = ys + B * N;
  float* centers = out + B * NG * GS * 3;  // center block of d_out

  transform_k<<<dim3((B * N + 255) / 256), dim3(256), 0, stream>>>(xyz, pose, xs, ys, zs);
  fps_k<<<dim3(B), dim3(FT), 0, stream>>>(xs, ys, zs, centers);
  knn_k<<<dim3(NG, B), dim3(KNN_T), 0, stream>>>(xs, ys, zs, centers, out);
}